// Round 11
// baseline (422.919 us; speedup 1.0000x reference)
//
#include <hip/hip_runtime.h>
#include <hip/hip_bf16.h>

#define N_NODES 150000
#define M_HYPER 50000
#define N_TOTAL 200000
#define DIM 64
#define NCLASS 50
#define NNZ 3200000

#define BSHIFT 9
#define BROWS 512
#define NBUK ((N_TOTAL + BROWS - 1) / BROWS)  // 391
#define EB 8192                               // edges per binning block
#define CAP 9216                              // fixed bucket capacity (11 sigma)

// ---------------------------------------------------------------------------
// Init fixed-capacity cursors: bcur[b] = b * CAP
// ---------------------------------------------------------------------------
__global__ __launch_bounds__(512) void init_cur(int* __restrict__ bcur) {
    int t = threadIdx.x;
    if (t < NBUK) bcur[t] = t * CAP;
}

// ---------------------------------------------------------------------------
// Phase A: bin edges into fixed-capacity bucket regions, LDS-aggregated.
// One global atomicAdd per (block, bucket) reserves a contiguous chunk.
// rec.x = (rrel << 18) | col, rec.y = f32 val bits
// ---------------------------------------------------------------------------
__global__ __launch_bounds__(1024) void bin_edges(
    const int* __restrict__ rows, const int* __restrict__ cols,
    const float* __restrict__ vals, int* __restrict__ bcur,
    int2* __restrict__ recs) {
    __shared__ int h[NBUK];
    __shared__ int lbase[NBUK];
    int base = blockIdx.x * EB;
    int cntE = NNZ - base; if (cntE > EB) cntE = EB;
    for (int i = threadIdx.x; i < NBUK; i += 1024) h[i] = 0;
    __syncthreads();
    for (int i = threadIdx.x; i < cntE; i += 1024)
        atomicAdd(&h[rows[base + i] >> BSHIFT], 1);
    __syncthreads();
    for (int i = threadIdx.x; i < NBUK; i += 1024) {
        int c = h[i];
        lbase[i] = c ? atomicAdd(&bcur[i], c) : 0;
    }
    __syncthreads();
    for (int i = threadIdx.x; i < NBUK; i += 1024) h[i] = 0;
    __syncthreads();
    for (int i = threadIdx.x; i < cntE; i += 1024) {
        int e = base + i;
        int r = rows[e];
        int b = r >> BSHIFT;
        int p = lbase[b] + atomicAdd(&h[b], 1);
        if (p < NBUK * CAP)  // statistically impossible overflow guard
            recs[p] = make_int2(((r & (BROWS - 1)) << 18) | cols[e],
                                __float_as_int(vals[e]));
    }
}

// ---------------------------------------------------------------------------
// Exclusive scan over actual bucket counts (bcur[b] - b*CAP) -> compact boff
// ---------------------------------------------------------------------------
__global__ __launch_bounds__(512) void cnt_scan(const int* __restrict__ bcur,
                                                int* __restrict__ boff) {
    __shared__ int sh[512];
    int t = threadIdx.x;
    int c = (t < NBUK) ? (bcur[t] - t * CAP) : 0;
    sh[t] = c;
    __syncthreads();
    for (int off = 1; off < 512; off <<= 1) {
        int v = (t >= off) ? sh[t - off] : 0;
        __syncthreads();
        sh[t] += v;
        __syncthreads();
    }
    if (t < NBUK) boff[t] = sh[t] - c;  // exclusive
    if (t == 0) boff[NBUK] = NNZ;
}

// ---------------------------------------------------------------------------
// Phase B: per-bucket exact CSR build. One workgroup per bucket, 512 thr.
// Reads recs from fixed region b*CAP, writes compact edges at boff[b].
// ---------------------------------------------------------------------------
__global__ __launch_bounds__(512) void build_csr(const int* __restrict__ boff,
                                                 const int2* __restrict__ recs,
                                                 int* __restrict__ row_ptr,
                                                 int2* __restrict__ edges) {
    __shared__ int h[BROWS];
    __shared__ int ps[BROWS];
    int b = blockIdx.x, t = threadIdx.x;
    int rbase = b * CAP;
    int obase = boff[b];
    int cnt = boff[b + 1] - obase;
    int row0 = b << BSHIFT;
    int nrows = N_TOTAL - row0;
    if (nrows > BROWS) nrows = BROWS;
    h[t] = 0;
    __syncthreads();
    for (int i = t; i < cnt; i += 512)
        atomicAdd(&h[recs[rbase + i].x >> 18], 1);
    __syncthreads();
    int v = h[t];
    ps[t] = v;
    __syncthreads();
    for (int off = 1; off < 512; off <<= 1) {
        int a = (t >= off) ? ps[t - off] : 0;
        __syncthreads();
        ps[t] += a;
        __syncthreads();
    }
    int start = obase + ps[t] - v;  // exclusive within bucket + global base
    if (t < nrows) row_ptr[row0 + t] = start;
    if (b == NBUK - 1 && t == 0) row_ptr[N_TOTAL] = NNZ;
    h[t] = start;  // reuse as scatter cursors
    __syncthreads();
    for (int i = t; i < cnt; i += 512) {
        int2 rc = recs[rbase + i];
        int p = atomicAdd(&h[rc.x >> 18], 1);
        edges[p] = make_int2(rc.x & 0x3FFFF, rc.y);
    }
}

// ---------------------------------------------------------------------------
// Build bf16 all_emb from f32 node_emb / hyper_emb. 4 elems per thread.
// ---------------------------------------------------------------------------
__global__ __launch_bounds__(256) void build_x_bf16(
    const float* __restrict__ node_emb, const float* __restrict__ hyper_emb,
    __hip_bfloat162* __restrict__ xb) {
    int i = blockIdx.x * 256 + threadIdx.x;
    size_t base = (size_t)i * 4;
    const size_t NN = (size_t)N_NODES * DIM;
    if (base >= (size_t)N_TOTAL * DIM) return;
    float4 f;
    if (base < NN)
        f = *reinterpret_cast<const float4*>(node_emb + base);
    else
        f = *reinterpret_cast<const float4*>(hyper_emb + (base - NN));
    xb[2 * i] = __float22bfloat162_rn(make_float2(f.x, f.y));
    xb[2 * i + 1] = __float22bfloat162_rn(make_float2(f.z, f.w));
}

// ---------------------------------------------------------------------------
// SpMM gather: 32 lanes per row (lane = 2 dims via ushort2), 2 rows per wave,
// unroll x8 per row. Edge stream loaded nontemporally (read-once) to keep
// the gather working set resident in L2.
// ---------------------------------------------------------------------------
__device__ __forceinline__ float2 bf2_to_f2(unsigned g) {
    float2 r;
    r.x = __uint_as_float(g << 16);
    r.y = __uint_as_float(g & 0xffff0000u);
    return r;
}

__device__ __forceinline__ void nt_edge(const int2* p, int& c, float& v) {
    long long raw = __builtin_nontemporal_load((const long long*)p);
    c = (int)(raw & 0xFFFFFFFFll);
    v = __int_as_float((int)(raw >> 32));
}

__global__ __launch_bounds__(256) void spmm_gather(
    const int* __restrict__ row_ptr, const int2* __restrict__ edges,
    const unsigned short* __restrict__ x, unsigned short* __restrict__ y,
    int nrows) {
    int gid = blockIdx.x * 256 + threadIdx.x;
    int row = gid >> 5;
    int lane = threadIdx.x & 31;
    if (row >= nrows) return;
    int beg = row_ptr[row], end = row_ptr[row + 1];
    float rx = 0.f, ry = 0.f;
    int k = beg;
    for (; k + 7 < end; k += 8) {
        int c[8]; float v[8];
        unsigned g[8];
#pragma unroll
        for (int j = 0; j < 8; ++j) nt_edge(edges + k + j, c[j], v[j]);
#pragma unroll
        for (int j = 0; j < 8; ++j)
            g[j] = *(const unsigned*)(x + ((size_t)c[j] << 6) + lane * 2);
#pragma unroll
        for (int j = 0; j < 8; ++j) {
            float2 f = bf2_to_f2(g[j]);
            rx = fmaf(v[j], f.x, rx);
            ry = fmaf(v[j], f.y, ry);
        }
    }
    for (; k + 3 < end; k += 4) {
        int c[4]; float v[4];
        unsigned g[4];
#pragma unroll
        for (int j = 0; j < 4; ++j) nt_edge(edges + k + j, c[j], v[j]);
#pragma unroll
        for (int j = 0; j < 4; ++j)
            g[j] = *(const unsigned*)(x + ((size_t)c[j] << 6) + lane * 2);
#pragma unroll
        for (int j = 0; j < 4; ++j) {
            float2 f = bf2_to_f2(g[j]);
            rx = fmaf(v[j], f.x, rx);
            ry = fmaf(v[j], f.y, ry);
        }
    }
    for (; k < end; ++k) {
        int c; float v;
        nt_edge(edges + k, c, v);
        unsigned g = *(const unsigned*)(x + ((size_t)c << 6) + lane * 2);
        float2 f = bf2_to_f2(g);
        rx = fmaf(v, f.x, rx);
        ry = fmaf(v, f.y, ry);
    }
    __hip_bfloat162 pk = __float22bfloat162_rn(make_float2(rx, ry));
    *(unsigned*)(y + ((size_t)row << 6) + lane * 2) =
        *reinterpret_cast<unsigned*>(&pk);
}

// ---------------------------------------------------------------------------
// Fused classifier: Z = log_softmax((node_emb + y1 + y2 + y3)/4 @ W + b)
// xr[64] in registers; classes iterated with #pragma unroll 1 (compact body,
// no z array -> no spill); W/bias via wave-uniform scalar loads (no LDS).
// Online-softmax pass + recompute-write pass.
// ---------------------------------------------------------------------------
__global__ __launch_bounds__(256) void classify(
    const float* __restrict__ node_emb, const unsigned short* __restrict__ y1,
    const unsigned short* __restrict__ y2,
    const unsigned short* __restrict__ y3, const float* __restrict__ W,
    const float* __restrict__ bias, float* __restrict__ Z) {
    int row = blockIdx.x * 256 + threadIdx.x;
    if (row >= N_NODES) return;
    const float4* np =
        reinterpret_cast<const float4*>(node_emb + (size_t)row * DIM);
    const unsigned* p1 = (const unsigned*)(y1 + ((size_t)row << 6));
    const unsigned* p2 = (const unsigned*)(y2 + ((size_t)row << 6));
    const unsigned* p3 = (const unsigned*)(y3 + ((size_t)row << 6));
    float xr[DIM];
#pragma unroll
    for (int i = 0; i < DIM / 4; ++i) {
        float4 f = np[i];
        float2 a0 = bf2_to_f2(p1[2 * i]), a1 = bf2_to_f2(p1[2 * i + 1]);
        float2 c0 = bf2_to_f2(p2[2 * i]), c1 = bf2_to_f2(p2[2 * i + 1]);
        float2 d0 = bf2_to_f2(p3[2 * i]), d1 = bf2_to_f2(p3[2 * i + 1]);
        xr[4 * i + 0] = (f.x + a0.x + c0.x + d0.x) * 0.25f;
        xr[4 * i + 1] = (f.y + a0.y + c0.y + d0.y) * 0.25f;
        xr[4 * i + 2] = (f.z + a1.x + c1.x + d1.x) * 0.25f;
        xr[4 * i + 3] = (f.w + a1.y + c1.y + d1.y) * 0.25f;
    }
    float m = -1e30f, s = 0.f;
#pragma unroll 1
    for (int c = 0; c < NCLASS; ++c) {
        float d = bias[c];
#pragma unroll
        for (int k = 0; k < DIM; ++k) d = fmaf(xr[k], W[k * NCLASS + c], d);
        float mn = fmaxf(m, d);
        s = s * __expf(m - mn) + __expf(d - mn);
        m = mn;
    }
    float ls = m + __logf(s);
    float* zp = Z + (size_t)row * NCLASS;
#pragma unroll 1
    for (int c = 0; c < NCLASS; ++c) {
        float d = bias[c];
#pragma unroll
        for (int k = 0; k < DIM; ++k) d = fmaf(xr[k], W[k * NCLASS + c], d);
        zp[c] = d - ls;
    }
}

extern "C" void kernel_launch(void* const* d_in, const int* in_sizes, int n_in,
                              void* d_out, int out_size, void* d_ws, size_t ws_size,
                              hipStream_t stream) {
    const float* node_emb = (const float*)d_in[0];
    const float* hyper_emb = (const float*)d_in[1];
    const float* W = (const float*)d_in[2];
    const float* b = (const float*)d_in[3];
    const float* vals = (const float*)d_in[4];
    const int* rows = (const int*)d_in[5];
    const int* cols = (const int*)d_in[6];
    float* Z = (float*)d_out;

    const size_t BUFB = (size_t)N_TOTAL * DIM * 2;  // 25.6 MB (bf16)
    const size_t EDG = (size_t)NNZ * 8;             // 25.6 MB (int2)

    char* w = (char*)d_ws;
    unsigned short* xb = (unsigned short*)w;  w += BUFB;
    unsigned short* y1 = (unsigned short*)w;  w += BUFB;
    unsigned short* y2 = (unsigned short*)w;  w += BUFB;
    unsigned short* y3 = (unsigned short*)w;  w += BUFB;
    int2* edges = (int2*)w;                   w += EDG;
    int* row_ptr = (int*)w;                   w += (size_t)(N_TOTAL + 1) * 4;
    int* boff = (int*)w;                      w += 2048;
    int* bcur = (int*)w;
    // recs aliases y2+y3 (51.2 MB >= 391*9216*8 = 28.8 MB); dead before pass 2.
    int2* recs = (int2*)y2;

    // ---- Bucketed CSR build (fixed-capacity regions, no pre-histogram) ----
    init_cur<<<1, 512, 0, stream>>>(bcur);
    const int bin_blocks = (NNZ + EB - 1) / EB;  // 391
    bin_edges<<<bin_blocks, 1024, 0, stream>>>(rows, cols, vals, bcur, recs);
    cnt_scan<<<1, 512, 0, stream>>>(bcur, boff);
    build_csr<<<NBUK, 512, 0, stream>>>(boff, recs, row_ptr, edges);

    // ---- Build bf16 all_emb ----
    const int cvt_blocks = (int)(((size_t)N_TOTAL * DIM / 4 + 255) / 256);
    build_x_bf16<<<cvt_blocks, 256, 0, stream>>>(node_emb, hyper_emb,
                                                 (__hip_bfloat162*)xb);

    const int out_blocks = (N_NODES + 255) / 256;
    const int full_blocks = (N_TOTAL * 32 + 255) / 256;
    const int node_blocks = (N_NODES * 32 + 255) / 256;

    // L1: y1 = A x
    spmm_gather<<<full_blocks, 256, 0, stream>>>(row_ptr, edges, xb, y1,
                                                 N_TOTAL);
    // L2: y2 = A y1
    spmm_gather<<<full_blocks, 256, 0, stream>>>(row_ptr, edges, y1, y2,
                                                 N_TOTAL);
    // L3: y3 = A y2 (node rows only)
    spmm_gather<<<node_blocks, 256, 0, stream>>>(row_ptr, edges, y2, y3,
                                                 N_NODES);
    classify<<<out_blocks, 256, 0, stream>>>(node_emb, y1, y2, y3, W, b, Z);
}